// Round 6
// baseline (784.478 us; speedup 1.0000x reference)
//
#include <hip/hip_runtime.h>
#include <stdint.h>

#define BATCH  4
#define SQ     2048
#define DMODEL 512
#define NH     8
#define DK     64

// mask offload: rows (b*NH+h)*SQ + q >= ROW_CUT have their mask bits
// precomputed into ws by the pre-attention kernels.
#define ROW_CUT   57344u                 // bh >= 28
#define W0        3670016u               // (ROW_CUT*2048)/32
#define NPAIR     524288u                // word-pairs offloaded (12.5%)

typedef __attribute__((ext_vector_type(8))) short short8;
typedef __attribute__((ext_vector_type(4))) float f32x4;

// ---------------- threefry2x32 (JAX-compatible, 20 rounds) ----------------
struct TFK { uint32_t a, b; };
constexpr uint32_t rotl_ce(uint32_t x, int d) {
  return (x << d) | (x >> (32 - d));
}
constexpr TFK tf_ce(uint32_t k0, uint32_t k1, uint32_t x0, uint32_t x1) {
  const uint32_t ks[3] = {k0, k1, k0 ^ k1 ^ 0x1BD11BDAu};
  const int rot[2][4] = {{13, 15, 26, 6}, {17, 29, 16, 24}};
  x0 += k0; x1 += k1;
  for (int c = 0; c < 5; ++c) {
    for (int j = 0; j < 4; ++j) {
      x0 += x1; x1 = rotl_ce(x1, rot[c & 1][j]); x1 ^= x0;
    }
    x0 += ks[(c + 1) % 3];
    x1 += ks[(c + 2) % 3] + (uint32_t)(c + 1);
  }
  return TFK{x0, x1};
}
constexpr TFK SPK = tf_ce(0u, 42u, 0u, 1u);  // fold_in(key(42), 1)
constexpr TFK DPK = tf_ce(0u, 42u, 0u, 2u);  // fold_in(key(42), 2)

#define SP_THR 0x80000200u
#define DP_THR 0x1999A200u

// Key-schedule constants as kernel args (SGPR-resident).
struct TfArgs {
  uint32_t sp[8];
  uint32_t dp[8];
  uint32_t sp_thr, dp_thr;
};

__device__ __forceinline__ void tf_round(uint32_t &x0, uint32_t &x1, int d) {
  x0 += x1;
  x1 = __builtin_amdgcn_alignbit(x1, x1, 32 - d);
  x1 ^= x0;
}
__device__ __forceinline__ void tf_grp(uint32_t &x0, uint32_t &x1,
                                       uint32_t injx1, uint32_t injx0, int d0,
                                       int d1, int d2, int d3) {
  x1 += injx1;
  x0 = x0 + injx0 + x1;
  x1 = __builtin_amdgcn_alignbit(x1, x1, 32 - d0);
  x1 ^= x0;
  tf_round(x0, x1, d1);
  tf_round(x0, x1, d2);
  tf_round(x0, x1, d3);
}
__device__ __forceinline__ uint32_t tf_rt(const uint32_t *__restrict__ c,
                                          uint32_t ctr) {
  uint32_t x1 = c[1] + ctr;
  uint32_t x0 = c[0] + x1;
  x1 = __builtin_amdgcn_alignbit(x1, x1, 19);
  x1 ^= x0;
  tf_round(x0, x1, 15);
  tf_round(x0, x1, 26);
  tf_round(x0, x1, 6);
  tf_grp(x0, x1, c[2], c[1], 17, 29, 16, 24);
  tf_grp(x0, x1, c[3], c[7], 13, 15, 26, 6);
  tf_grp(x0, x1, c[4], c[0], 17, 29, 16, 24);
  tf_grp(x0, x1, c[5], c[1], 13, 15, 26, 6);
  return (x0 + c[7]) ^ (x1 + c[6]);
}

// one offloaded word-pair: 32 ctrs -> one sparsity word + one dropout word
__device__ __forceinline__ void gen_mask_pair(uint32_t pairidx,
                                              const TfArgs &ta,
                                              uint32_t *__restrict__ spw,
                                              uint32_t *__restrict__ dpw) {
  const uint32_t base = (W0 + pairidx) << 5;
  uint32_t sw = 0u, dw = 0u;
#pragma unroll 4
  for (uint32_t t = 0; t < 32; ++t) {
    sw |= (tf_rt(ta.sp, base + t) >= ta.sp_thr ? 1u : 0u) << t;
    dw |= (tf_rt(ta.dp, base + t) >= ta.dp_thr ? 1u : 0u) << t;
  }
  spw[pairidx] = sw;
  dpw[pairidx] = dw;
}

__device__ __forceinline__ ushort f2bf_rne(float f) {
  uint32_t u = __float_as_uint(f);
  return (ushort)((u + 0x7fffu + ((u >> 16) & 1u)) >> 16);
}
__device__ __forceinline__ float bf2f(ushort h) {
  return __uint_as_float((uint32_t)h << 16);
}
__device__ __forceinline__ float exp_scaled(float s) {  // exp(s/8)
#if __has_builtin(__builtin_amdgcn_exp2f)
  return __builtin_amdgcn_exp2f(s * 0.18033688011112042f);
#else
  return __expf(s * 0.125f);
#endif
}

// ---------------- hi/lo split prep kernels ---------------------------------
__device__ __forceinline__ void split4(const float *__restrict__ src,
                                       ushort *__restrict__ dh,
                                       ushort *__restrict__ dl, size_t base) {
  float4 x = *(const float4 *)(src + base);
  uint32_t h[4], lo[4];
#pragma unroll
  for (int i = 0; i < 4; ++i) {
    float xi = ((const float *)&x)[i];
    ushort hh = f2bf_rne(xi);
    h[i] = hh;
    lo[i] = f2bf_rne(xi - bf2f(hh));
  }
  uint2 ph, pl;
  ph.x = h[0] | (h[1] << 16);  ph.y = h[2] | (h[3] << 16);
  pl.x = lo[0] | (lo[1] << 16); pl.y = lo[2] | (lo[3] << 16);
  *(uint2 *)(dh + base) = ph;
  *(uint2 *)(dl + base) = pl;
}

// masks pairs [0, 131072)
__global__ __launch_bounds__(256) void split_inputs_k(
    const float *__restrict__ q, const float *__restrict__ k,
    const float *__restrict__ v, ushort *__restrict__ qh,
    ushort *__restrict__ ql, ushort *__restrict__ kh, ushort *__restrict__ kl,
    ushort *__restrict__ vh, ushort *__restrict__ vl,
    uint32_t *__restrict__ spw, uint32_t *__restrict__ dpw, TfArgs ta) {
  const float *src = blockIdx.y == 0 ? q : (blockIdx.y == 1 ? k : v);
  ushort *dh = blockIdx.y == 0 ? qh : (blockIdx.y == 1 ? kh : vh);
  ushort *dl = blockIdx.y == 0 ? ql : (blockIdx.y == 1 ? kl : vl);
  const size_t base = ((size_t)blockIdx.x * 256 + threadIdx.x) * 4;
  split4(src, dh, dl, base);
  const uint32_t flat =
      (blockIdx.y * 4096u + blockIdx.x) * 256u + threadIdx.x;
  if (flat < 131072u) gen_mask_pair(flat, ta, spw, dpw);
}

// masks pairs [131072, 163840)
__global__ __launch_bounds__(256) void split_w_k(
    const float *__restrict__ w0, const float *__restrict__ w1,
    const float *__restrict__ w2, const float *__restrict__ w3,
    ushort *__restrict__ h0, ushort *__restrict__ l0, ushort *__restrict__ h1,
    ushort *__restrict__ l1, ushort *__restrict__ h2, ushort *__restrict__ l2,
    ushort *__restrict__ h3, ushort *__restrict__ l3,
    uint32_t *__restrict__ spw, uint32_t *__restrict__ dpw, TfArgs ta) {
  const int y = blockIdx.y;
  const float *src = y == 0 ? w0 : (y == 1 ? w1 : (y == 2 ? w2 : w3));
  ushort *dh = y == 0 ? h0 : (y == 1 ? h1 : (y == 2 ? h2 : h3));
  ushort *dl = y == 0 ? l0 : (y == 1 ? l1 : (y == 2 ? l2 : l3));
  const size_t base = ((size_t)blockIdx.x * 256 + threadIdx.x) * 4;
  split4(src, dh, dl, base);
  const uint32_t flat = (blockIdx.y * 256u + blockIdx.x) * 256u + threadIdx.x;
  if (flat < 32768u) gen_mask_pair(131072u + flat, ta, spw, dpw);
}

// ---------------- hi/lo bf16 MFMA GEMM: D = A @ B^T (+bias) ----------------
// MODE 0: fp32 out.  MODE 1: bf16 out.  MODE 2: bf16 transposed vpt via LDS.
// Also generates mask pairs [mbase, mbase+mcount) with its first mcount threads.
template <int MODE>
__global__ __launch_bounds__(256) void proj_mfma(
    const ushort *__restrict__ Ah, const ushort *__restrict__ Al,
    const ushort *__restrict__ Bh, const ushort *__restrict__ Bl,
    const float *__restrict__ bias, void *__restrict__ Yv,
    uint32_t mbase, uint32_t mcount, uint32_t *__restrict__ spw,
    uint32_t *__restrict__ dpw, TfArgs ta) {
  __shared__ ushort Tt[MODE == 2 ? 128 * 72 : 1];
  const int tid = threadIdx.x;
  const int w = tid >> 6, l = tid & 63;
  const int lr = l & 15, lq = l >> 4;
  const int am = blockIdx.y * 128 + w * 32;
  const int bn = blockIdx.x * 64;
  f32x4 acc[2][4];
#pragma unroll
  for (int i = 0; i < 2; ++i)
#pragma unroll
    for (int j = 0; j < 4; ++j) acc[i][j] = (f32x4){0.f, 0.f, 0.f, 0.f};

#pragma unroll 2
  for (int k0 = 0; k0 < DMODEL; k0 += 32) {
    short8 ah[2], al[2], bh[4], bl[4];
#pragma unroll
    for (int mf = 0; mf < 2; ++mf) {
      const size_t off = (size_t)(am + mf * 16 + lr) * DMODEL + k0 + lq * 8;
      ah[mf] = *(const short8 *)(Ah + off);
      al[mf] = *(const short8 *)(Al + off);
    }
#pragma unroll
    for (int nf = 0; nf < 4; ++nf) {
      const size_t off = (size_t)(bn + nf * 16 + lr) * DMODEL + k0 + lq * 8;
      bh[nf] = *(const short8 *)(Bh + off);
      bl[nf] = *(const short8 *)(Bl + off);
    }
#pragma unroll
    for (int mf = 0; mf < 2; ++mf)
#pragma unroll
      for (int nf = 0; nf < 4; ++nf) {
        acc[mf][nf] = __builtin_amdgcn_mfma_f32_16x16x32_bf16(
            ah[mf], bh[nf], acc[mf][nf], 0, 0, 0);
        acc[mf][nf] = __builtin_amdgcn_mfma_f32_16x16x32_bf16(
            ah[mf], bl[nf], acc[mf][nf], 0, 0, 0);
        acc[mf][nf] = __builtin_amdgcn_mfma_f32_16x16x32_bf16(
            al[mf], bh[nf], acc[mf][nf], 0, 0, 0);
      }
  }

  if (MODE == 2) {
#pragma unroll
    for (int mf = 0; mf < 2; ++mf)
#pragma unroll
      for (int nf = 0; nf < 4; ++nf) {
        const int gn2 = am + mf * 16 + lq * 4;
#pragma unroll
        for (int r = 0; r < 4; ++r) {
          const int featl = (w * 32 + mf * 16 + lq * 4 + r);
          Tt[featl * 72 + nf * 16 + lr] =
              f2bf_rne(acc[mf][nf][r] + bias[gn2 + r]);
        }
      }
    __syncthreads();
    ushort *Y = (ushort *)Yv;
    const int feat = tid >> 1, half = tid & 1;
    const int gfeat = blockIdx.y * 128 + feat;
    const int bcol = bn >> 11, scol = (bn & 2047) + half * 32;
    ushort *dst = Y + ((size_t)(bcol * DMODEL + gfeat)) * SQ + scol;
    const ushort *srcp = &Tt[feat * 72 + half * 32];
#pragma unroll
    for (int j = 0; j < 4; ++j)
      *(uint4 *)(dst + j * 8) = *(const uint4 *)(srcp + j * 8);
  } else {
#pragma unroll
    for (int mf = 0; mf < 2; ++mf)
#pragma unroll
      for (int nf = 0; nf < 4; ++nf) {
        const int gn = bn + nf * 16 + lr;
        const float bb = bias[gn];
        if (MODE == 0) {
          float *Y = (float *)Yv;
#pragma unroll
          for (int r = 0; r < 4; ++r) {
            const int gm = am + mf * 16 + lq * 4 + r;
            Y[(size_t)gm * DMODEL + gn] = acc[mf][nf][r] + bb;
          }
        } else {
          ushort *Y = (ushort *)Yv;
#pragma unroll
          for (int r = 0; r < 4; ++r) {
            const int gm = am + mf * 16 + lq * 4 + r;
            Y[(size_t)gm * DMODEL + gn] = f2bf_rne(acc[mf][nf][r] + bb);
          }
        }
      }
  }

  if (mcount) {
    const uint32_t flat =
        (blockIdx.y * gridDim.x + blockIdx.x) * 256u + threadIdx.x;
    if (flat < mcount) gen_mask_pair(mbase + flat, ta, spw, dpw);
  }
}

// ---------------- MFMA attention, fused masks, double-buffered staging ------
__global__ __launch_bounds__(256, 2) void attn_mfma(
    const ushort *__restrict__ qp, const ushort *__restrict__ kp,
    const ushort *__restrict__ vpt, ushort *__restrict__ xah,
    ushort *__restrict__ xal, const uint32_t *__restrict__ spw,
    const uint32_t *__restrict__ dpw, TfArgs ta) {
  __shared__ __align__(16) uint8_t lds[40960];
  const int b = blockIdx.z, h = blockIdx.y;
  const int qb = blockIdx.x * 64;
  const int tid = threadIdx.x;
  const int w = tid >> 6, l = tid & 63;
  const int lr = l & 15, lq = l >> 4;
  uint8_t *Ps = lds + 32768 + w * 2048;
  const int bh = b * NH + h;
  const bool use_pre = (uint32_t)(bh * SQ + qb) >= ROW_CUT;  // whole block

  short8 qf[2];
  {
    const int qrow = qb + w * 16 + lr;
    const ushort *qrowp = qp + ((size_t)(b * SQ + qrow)) * DMODEL + h * DK;
    qf[0] = *(const short8 *)(qrowp + lq * 8);
    qf[1] = *(const short8 *)(qrowp + 32 + lq * 8);
  }
  f32x4 o[4];
  f32x4 lacc;
#pragma unroll
  for (int nd = 0; nd < 4; ++nd) o[nd] = (f32x4){0.f, 0.f, 0.f, 0.f};
  lacc = (f32x4){0.f, 0.f, 0.f, 0.f};

  uint32_t rowflat[4], rowcomp[4];
#pragma unroll
  for (int r = 0; r < 4; ++r) {
    const uint32_t rowidx = (uint32_t)(bh * SQ + qb + w * 16 + lq * 4 + r);
    rowflat[r] = rowidx << 11;
    rowcomp[r] = (rowidx - ROW_CUT) * 64u;  // word base in compact arrays
  }

  const int srow = tid >> 2;
  const int sc0 = (tid & 3) * 2;
  const int ssw = (srow & 7) << 4;
  const ushort *kbase =
      kp + ((size_t)(b * SQ) + srow) * DMODEL + h * DK + sc0 * 8;
  const ushort *vbase = vpt + ((size_t)(bh * DK + srow)) * SQ + sc0 * 8;
  const int la0 = (srow * 128 + sc0 * 16) ^ ssw;
  const int la1 = (srow * 128 + (sc0 + 1) * 16) ^ ssw;

  uint4 kr0, kr1, vr0, vr1;
#define ISSUE(kv_)                                            \
  {                                                           \
    const ushort *ks_ = kbase + (size_t)(kv_)*DMODEL;         \
    kr0 = *(const uint4 *)ks_;                                \
    kr1 = *(const uint4 *)(ks_ + 8);                          \
    const ushort *vs_ = vbase + (kv_);                        \
    vr0 = *(const uint4 *)vs_;                                \
    vr1 = *(const uint4 *)(vs_ + 8);                          \
  }
#define STORE(buf_)                                           \
  {                                                           \
    uint8_t *Kb_ = lds + (buf_)*8192;                         \
    uint8_t *Vb_ = lds + 16384 + (buf_)*8192;                 \
    *(uint4 *)(Kb_ + la0) = kr0;                              \
    *(uint4 *)(Kb_ + la1) = kr1;                              \
    *(uint4 *)(Vb_ + la0) = vr0;                              \
    *(uint4 *)(Vb_ + la1) = vr1;                              \
  }

  ISSUE(0)
  STORE(0)
  __syncthreads();

  for (int kv = 0; kv < SQ; kv += 64) {
    const int cur = (kv >> 6) & 1;
    uint8_t *Ks = lds + cur * 8192;
    uint8_t *Vt = lds + 16384 + cur * 8192;
    const bool more = (kv + 64) < SQ;
    if (more) ISSUE(kv + 64)

    f32x4 s[4];
#pragma unroll
    for (int ni = 0; ni < 4; ++ni) s[ni] = (f32x4){0.f, 0.f, 0.f, 0.f};
#pragma unroll
    for (int ni = 0; ni < 4; ++ni) {
      const int krow = ni * 16 + lr;
      const int sw = (krow & 7) << 4;
#pragma unroll
      for (int kf = 0; kf < 2; ++kf) {
        short8 kb =
            *(const short8 *)(Ks + ((krow * 128 + kf * 64 + lq * 16) ^ sw));
        s[ni] =
            __builtin_amdgcn_mfma_f32_16x16x32_bf16(qf[kf], kb, s[ni], 0, 0, 0);
      }
    }

    auto process = [&](int ni, int r, bool keep_s, bool keep_d) {
      float e = exp_scaled(s[ni][r]);
      float p = keep_s ? e : 0.0f;
      lacc[r] += p;
      float pd = keep_d ? p * (1.0f / 0.9f) : 0.0f;
      const int prow = lq * 4 + r;
      *(ushort *)(Ps +
                  ((prow * 128 + (ni * 16 + lr) * 2) ^ ((prow & 7) << 4))) =
          f2bf_rne(pd);
    };

    if (!use_pre) {
      const uint32_t colbase = (uint32_t)(kv + lr);
#pragma unroll
      for (int ni = 0; ni < 4; ++ni) {
#pragma unroll
        for (int r = 0; r < 4; ++r) {
          const uint32_t ctr = rowflat[r] + colbase + (uint32_t)(ni * 16);
          process(ni, r, tf_rt(ta.sp, ctr) >= ta.sp_thr,
                  tf_rt(ta.dp, ctr) >= ta.dp_thr);
        }
      }
    } else {
      uint2 swd[4], dwd[4];
#pragma unroll
      for (int r = 0; r < 4; ++r) {
        const uint32_t wb = rowcomp[r] + (uint32_t)(kv >> 5);
        swd[r] = *(const uint2 *)(spw + wb);
        dwd[r] = *(const uint2 *)(dpw + wb);
      }
#pragma unroll
      for (int ni = 0; ni < 4; ++ni) {
        const int bpos = (ni & 1) * 16 + lr;
#pragma unroll
        for (int r = 0; r < 4; ++r) {
          const uint32_t sws = (ni < 2) ? swd[r].x : swd[r].y;
          const uint32_t dws = (ni < 2) ? dwd[r].x : dwd[r].y;
          process(ni, r, (sws >> bpos) & 1u, (dws >> bpos) & 1u);
        }
      }
    }

#pragma unroll
    for (int kf = 0; kf < 2; ++kf) {
      short8 pa = *(const short8 *)(Ps + ((lr * 128 + kf * 64 + lq * 16) ^
                                          ((lr & 7) << 4)));
#pragma unroll
      for (int nd = 0; nd < 4; ++nd) {
        const int vrow = nd * 16 + lr;
        short8 vb = *(const short8 *)(Vt + ((vrow * 128 + kf * 64 + lq * 16) ^
                                            ((vrow & 7) << 4)));
        o[nd] = __builtin_amdgcn_mfma_f32_16x16x32_bf16(pa, vb, o[nd], 0, 0, 0);
      }
    }

    if (more) STORE(cur ^ 1)
    __syncthreads();
  }
#undef ISSUE
#undef STORE

  float inv[4];
#pragma unroll
  for (int r = 0; r < 4; ++r) {
    float t = lacc[r];
    t += __shfl_xor(t, 1);
    t += __shfl_xor(t, 2);
    t += __shfl_xor(t, 4);
    t += __shfl_xor(t, 8);
    inv[r] = 1.0f / t;
  }
#pragma unroll
  for (int nd = 0; nd < 4; ++nd)
#pragma unroll
    for (int r = 0; r < 4; ++r) {
      const int qrow = qb + w * 16 + lq * 4 + r;
      const size_t idx =
          ((size_t)(b * SQ + qrow)) * DMODEL + h * DK + nd * 16 + lr;
      const float val = o[nd][r] * inv[r];
      const ushort hh = f2bf_rne(val);
      xah[idx] = hh;
      xal[idx] = f2bf_rne(val - bf2f(hh));
    }
}

// ---------------------------------------------------------------------------
extern "C" void kernel_launch(void *const *d_in, const int *in_sizes, int n_in,
                              void *d_out, int out_size, void *d_ws,
                              size_t ws_size, hipStream_t stream) {
  (void)in_sizes; (void)n_in; (void)out_size;
  const float *query = (const float *)d_in[0];
  const float *key_  = (const float *)d_in[1];
  const float *value = (const float *)d_in[2];
  const float *Wq = (const float *)d_in[3];
  const float *bq = (const float *)d_in[4];
  const float *Wk = (const float *)d_in[5];
  const float *bk = (const float *)d_in[6];
  const float *Wv = (const float *)d_in[7];
  const float *bv = (const float *)d_in[8];
  const float *Wo = (const float *)d_in[9];
  const float *bo = (const float *)d_in[10];
  float *out = (float *)d_out;

  const size_t MB = (size_t)1 << 20;
  if (ws_size < 96 * MB) return;

  char *ws = (char *)d_ws;
  ushort *qih = (ushort *)(ws);
  ushort *qil = (ushort *)(ws + 8 * MB);
  ushort *kih = (ushort *)(ws + 16 * MB);
  ushort *kil = (ushort *)(ws + 24 * MB);
  ushort *vih = (ushort *)(ws + 32 * MB);
  ushort *vil = (ushort *)(ws + 40 * MB);
  ushort *Wqh = (ushort *)(ws + 48 * MB);
  ushort *Wql = (ushort *)(ws + 48 * MB + 512 * 1024);
  ushort *Wkh = (ushort *)(ws + 49 * MB);
  ushort *Wkl = (ushort *)(ws + 49 * MB + 512 * 1024);
  ushort *Wvh = (ushort *)(ws + 50 * MB);
  ushort *Wvl = (ushort *)(ws + 50 * MB + 512 * 1024);
  ushort *Woh = (ushort *)(ws + 51 * MB);
  ushort *Wol = (ushort *)(ws + 51 * MB + 512 * 1024);
  ushort *qp  = (ushort *)(ws + 52 * MB);
  ushort *kp  = (ushort *)(ws + 60 * MB);
  ushort *vpt = (ushort *)(ws + 68 * MB);
  ushort *xah = (ushort *)(ws + 76 * MB);
  ushort *xal = (ushort *)(ws + 84 * MB);
  uint32_t *spw = (uint32_t *)(ws + 92 * MB);  // 2 MB (NPAIR words)
  uint32_t *dpw = (uint32_t *)(ws + 94 * MB);  // 2 MB

  constexpr uint32_t KS2s = SPK.a ^ SPK.b ^ 0x1BD11BDAu;
  constexpr uint32_t KS2d = DPK.a ^ DPK.b ^ 0x1BD11BDAu;
  TfArgs ta = {
      {SPK.a, SPK.b, KS2s + 1u, SPK.a + 2u, SPK.b + 3u, KS2s + 4u, SPK.a + 5u,
       KS2s},
      {DPK.a, DPK.b, KS2d + 1u, DPK.a + 2u, DPK.b + 3u, KS2d + 4u, DPK.a + 5u,
       KS2d},
      SP_THR, DP_THR};

  split_inputs_k<<<dim3(4096, 3), 256, 0, stream>>>(
      query, key_, value, qih, qil, kih, kil, vih, vil, spw, dpw, ta);
  split_w_k<<<dim3(256, 4), 256, 0, stream>>>(Wq, Wk, Wv, Wo, Wqh, Wql, Wkh,
                                              Wkl, Wvh, Wvl, Woh, Wol, spw,
                                              dpw, ta);

  proj_mfma<1><<<dim3(8, 64), 256, 0, stream>>>(qih, qil, Wqh, Wql, bq, qp,
                                                163840u, 131072u, spw, dpw, ta);
  proj_mfma<1><<<dim3(8, 64), 256, 0, stream>>>(kih, kil, Wkh, Wkl, bk, kp,
                                                294912u, 131072u, spw, dpw, ta);
  proj_mfma<2><<<dim3(128, 4), 256, 0, stream>>>(Wvh, Wvl, vih, vil, bv, vpt,
                                                 425984u, 98304u, spw, dpw, ta);

  attn_mfma<<<dim3(SQ / 64, NH, BATCH), 256, 0, stream>>>(qp, kp, vpt, xah,
                                                          xal, spw, dpw, ta);

  proj_mfma<0><<<dim3(8, 64), 256, 0, stream>>>(xah, xal, Woh, Wol, bo, out, 0u,
                                                0u, spw, dpw, ta);
}

// Round 7
// 757.976 us; speedup vs baseline: 1.0350x; 1.0350x over previous
//
#include <hip/hip_runtime.h>
#include <stdint.h>

#define BATCH  4
#define SQ     2048
#define DMODEL 512
#define NH     8
#define DK     64

typedef __attribute__((ext_vector_type(8))) short short8;
typedef __attribute__((ext_vector_type(4))) float f32x4;

// ---------------- threefry2x32 (JAX-compatible, 20 rounds) ----------------
struct TFK { uint32_t a, b; };
constexpr uint32_t rotl_ce(uint32_t x, int d) {
  return (x << d) | (x >> (32 - d));
}
constexpr TFK tf_ce(uint32_t k0, uint32_t k1, uint32_t x0, uint32_t x1) {
  const uint32_t ks[3] = {k0, k1, k0 ^ k1 ^ 0x1BD11BDAu};
  const int rot[2][4] = {{13, 15, 26, 6}, {17, 29, 16, 24}};
  x0 += k0; x1 += k1;
  for (int c = 0; c < 5; ++c) {
    for (int j = 0; j < 4; ++j) {
      x0 += x1; x1 = rotl_ce(x1, rot[c & 1][j]); x1 ^= x0;
    }
    x0 += ks[(c + 1) % 3];
    x1 += ks[(c + 2) % 3] + (uint32_t)(c + 1);
  }
  return TFK{x0, x1};
}
constexpr TFK SPK = tf_ce(0u, 42u, 0u, 1u);  // fold_in(key(42), 1)
constexpr TFK DPK = tf_ce(0u, 42u, 0u, 2u);  // fold_in(key(42), 2)

#define SP_THR 0x80000200u
#define DP_THR 0x1999A200u

// Key-schedule constants as kernel args (SGPR-resident).
struct TfArgs {
  uint32_t sp[8];
  uint32_t dp[8];
  uint32_t sp_thr, dp_thr;
};

__device__ __forceinline__ void tf_round(uint32_t &x0, uint32_t &x1, int d) {
  x0 += x1;
  x1 = __builtin_amdgcn_alignbit(x1, x1, 32 - d);
  x1 ^= x0;
}
__device__ __forceinline__ void tf_grp(uint32_t &x0, uint32_t &x1,
                                       uint32_t injx1, uint32_t injx0, int d0,
                                       int d1, int d2, int d3) {
  x1 += injx1;
  x0 = x0 + injx0 + x1;
  x1 = __builtin_amdgcn_alignbit(x1, x1, 32 - d0);
  x1 ^= x0;
  tf_round(x0, x1, d1);
  tf_round(x0, x1, d2);
  tf_round(x0, x1, d3);
}
__device__ __forceinline__ uint32_t tf_rt(const uint32_t *__restrict__ c,
                                          uint32_t ctr) {
  uint32_t x1 = c[1] + ctr;
  uint32_t x0 = c[0] + x1;
  x1 = __builtin_amdgcn_alignbit(x1, x1, 19);
  x1 ^= x0;
  tf_round(x0, x1, 15);
  tf_round(x0, x1, 26);
  tf_round(x0, x1, 6);
  tf_grp(x0, x1, c[2], c[1], 17, 29, 16, 24);
  tf_grp(x0, x1, c[3], c[7], 13, 15, 26, 6);
  tf_grp(x0, x1, c[4], c[0], 17, 29, 16, 24);
  tf_grp(x0, x1, c[5], c[1], 13, 15, 26, 6);
  return (x0 + c[7]) ^ (x1 + c[6]);
}

__device__ __forceinline__ ushort f2bf_rne(float f) {
  uint32_t u = __float_as_uint(f);
  return (ushort)((u + 0x7fffu + ((u >> 16) & 1u)) >> 16);
}
__device__ __forceinline__ float bf2f(ushort h) {
  return __uint_as_float((uint32_t)h << 16);
}
__device__ __forceinline__ float exp_scaled(float s) {  // exp(s/8)
#if __has_builtin(__builtin_amdgcn_exp2f)
  return __builtin_amdgcn_exp2f(s * 0.18033688011112042f);
#else
  return __expf(s * 0.125f);
#endif
}

// ---------------- hi/lo split: value + 4 weights in ONE kernel --------------
__device__ __forceinline__ void split4(const float *__restrict__ src,
                                       ushort *__restrict__ dh,
                                       ushort *__restrict__ dl, size_t base) {
  float4 x = *(const float4 *)(src + base);
  uint32_t h[4], lo[4];
#pragma unroll
  for (int i = 0; i < 4; ++i) {
    float xi = ((const float *)&x)[i];
    ushort hh = f2bf_rne(xi);
    h[i] = hh;
    lo[i] = f2bf_rne(xi - bf2f(hh));
  }
  uint2 ph, pl;
  ph.x = h[0] | (h[1] << 16);  ph.y = h[2] | (h[3] << 16);
  pl.x = lo[0] | (lo[1] << 16); pl.y = lo[2] | (lo[3] << 16);
  *(uint2 *)(dh + base) = ph;
  *(uint2 *)(dl + base) = pl;
}

__global__ __launch_bounds__(256) void split_all(
    const float *__restrict__ value, const float *__restrict__ Wq,
    const float *__restrict__ Wk, const float *__restrict__ Wv,
    const float *__restrict__ Wo, ushort *__restrict__ vh,
    ushort *__restrict__ vl, ushort *__restrict__ Wqh,
    ushort *__restrict__ Wql, ushort *__restrict__ Wkh,
    ushort *__restrict__ Wkl, ushort *__restrict__ Wvh,
    ushort *__restrict__ Wvl, ushort *__restrict__ Woh,
    ushort *__restrict__ Wol) {
  const int bid = blockIdx.x;
  const float *src;
  ushort *dh, *dl;
  uint32_t lb;
  if (bid < 4096) {  // value: 4.19M elems
    src = value; dh = vh; dl = vl; lb = bid;
  } else {
    const int t = bid - 4096;
    const int wsel = t >> 8;  // 256 blocks per weight
    lb = t & 255;
    src = wsel == 0 ? Wq : (wsel == 1 ? Wk : (wsel == 2 ? Wv : Wo));
    dh = wsel == 0 ? Wqh : (wsel == 1 ? Wkh : (wsel == 2 ? Wvh : Woh));
    dl = wsel == 0 ? Wql : (wsel == 1 ? Wkl : (wsel == 2 ? Wvl : Wol));
  }
  const size_t base = ((size_t)lb * 256 + threadIdx.x) * 4;
  split4(src, dh, dl, base);
}

// ---------------- hi/lo bf16 MFMA GEMM body: D = A @ B^T (+bias) ------------
// Wave = 16 A-rows x NF*16 B-rows. Block = 4 waves (BM=64).
// ASPL: A read as fp32 and hi/lo-split in-register (bit-identical to split4).
// FOUT: fp32 output, else bf16.
template <int NF, bool ASPL, bool FOUT>
__device__ __forceinline__ void proj_body(
    const float *__restrict__ Af, const ushort *__restrict__ Ah,
    const ushort *__restrict__ Al, const ushort *__restrict__ Bh,
    const ushort *__restrict__ Bl, const float *__restrict__ bias,
    void *__restrict__ Yv, int am, int bn, int lr, int lq) {
  f32x4 acc[NF];
#pragma unroll
  for (int nf = 0; nf < NF; ++nf) acc[nf] = (f32x4){0.f, 0.f, 0.f, 0.f};
  const int arow = am + lr;

#pragma unroll 1
  for (int k0 = 0; k0 < DMODEL; k0 += 32) {
    short8 ah, al;
    if (ASPL) {
      const float *ap = Af + (size_t)arow * DMODEL + k0 + lq * 8;
      float4 x0 = *(const float4 *)ap;
      float4 x1 = *(const float4 *)(ap + 4);
      float xs[8] = {x0.x, x0.y, x0.z, x0.w, x1.x, x1.y, x1.z, x1.w};
#pragma unroll
      for (int i = 0; i < 8; ++i) {
        const ushort hh = f2bf_rne(xs[i]);
        ((ushort *)&ah)[i] = hh;
        ((ushort *)&al)[i] = f2bf_rne(xs[i] - bf2f(hh));
      }
    } else {
      const size_t off = (size_t)arow * DMODEL + k0 + lq * 8;
      ah = *(const short8 *)(Ah + off);
      al = *(const short8 *)(Al + off);
    }
#pragma unroll
    for (int nf = 0; nf < NF; ++nf) {
      const size_t off = (size_t)(bn + nf * 16 + lr) * DMODEL + k0 + lq * 8;
      short8 bh = *(const short8 *)(Bh + off);
      short8 bl = *(const short8 *)(Bl + off);
      acc[nf] = __builtin_amdgcn_mfma_f32_16x16x32_bf16(ah, bh, acc[nf], 0, 0, 0);
      acc[nf] = __builtin_amdgcn_mfma_f32_16x16x32_bf16(ah, bl, acc[nf], 0, 0, 0);
      acc[nf] = __builtin_amdgcn_mfma_f32_16x16x32_bf16(al, bh, acc[nf], 0, 0, 0);
    }
  }

#pragma unroll
  for (int nf = 0; nf < NF; ++nf) {
    const int gn = bn + nf * 16 + lr;
    const float bb = bias[gn];
#pragma unroll
    for (int r = 0; r < 4; ++r) {
      const int gm = am + lq * 4 + r;
      if (FOUT)
        ((float *)Yv)[(size_t)gm * DMODEL + gn] = acc[nf][r] + bb;
      else
        ((ushort *)Yv)[(size_t)gm * DMODEL + gn] = f2bf_rne(acc[nf][r] + bb);
    }
  }
}

// Q and K projections fused in one launch (blockIdx.z), A = fp32 in-reg split.
__global__ __launch_bounds__(256) void proj_qk(
    const float *__restrict__ q, const float *__restrict__ k,
    const ushort *__restrict__ Wqh, const ushort *__restrict__ Wql,
    const ushort *__restrict__ Wkh, const ushort *__restrict__ Wkl,
    const float *__restrict__ bq, const float *__restrict__ bk,
    ushort *__restrict__ qp, ushort *__restrict__ kp) {
  const int tid = threadIdx.x;
  const int w = tid >> 6, l = tid & 63;
  const int lr = l & 15, lq = l >> 4;
  const int am = blockIdx.y * 64 + w * 16;
  const int bn = blockIdx.x * 256;
  if (blockIdx.z == 0)
    proj_body<16, true, false>(q, nullptr, nullptr, Wqh, Wql, bq, qp, am, bn,
                               lr, lq);
  else
    proj_body<16, true, false>(k, nullptr, nullptr, Wkh, Wkl, bk, kp, am, bn,
                               lr, lq);
}

// Output projection: A = xah/xal (presplit by attn), fp32 out.
__global__ __launch_bounds__(256) void proj_out(
    const ushort *__restrict__ xah, const ushort *__restrict__ xal,
    const ushort *__restrict__ Woh, const ushort *__restrict__ Wol,
    const float *__restrict__ bo, float *__restrict__ out) {
  const int tid = threadIdx.x;
  const int w = tid >> 6, l = tid & 63;
  const int lr = l & 15, lq = l >> 4;
  const int am = blockIdx.y * 64 + w * 16;
  const int bn = blockIdx.x * 128;
  proj_body<8, false, true>(nullptr, xah, xal, Woh, Wol, bo, out, am, bn, lr,
                            lq);
}

// V projection writing per-head V^T (R5 MODE2, verbatim geometry):
// A = Wv (M=512 feats, BM=128), B = value (N=8192 rows, BN=64), LDS transpose.
__global__ __launch_bounds__(256) void proj_vt(
    const ushort *__restrict__ Ah, const ushort *__restrict__ Al,
    const ushort *__restrict__ Bh, const ushort *__restrict__ Bl,
    const float *__restrict__ bias, ushort *__restrict__ Y) {
  __shared__ ushort Tt[128 * 72];
  const int tid = threadIdx.x;
  const int w = tid >> 6, l = tid & 63;
  const int lr = l & 15, lq = l >> 4;
  const int am = blockIdx.y * 128 + w * 32;
  const int bn = blockIdx.x * 64;
  f32x4 acc[2][4];
#pragma unroll
  for (int i = 0; i < 2; ++i)
#pragma unroll
    for (int j = 0; j < 4; ++j) acc[i][j] = (f32x4){0.f, 0.f, 0.f, 0.f};

#pragma unroll 2
  for (int k0 = 0; k0 < DMODEL; k0 += 32) {
    short8 ah[2], al[2], bh[4], bl[4];
#pragma unroll
    for (int mf = 0; mf < 2; ++mf) {
      const size_t off = (size_t)(am + mf * 16 + lr) * DMODEL + k0 + lq * 8;
      ah[mf] = *(const short8 *)(Ah + off);
      al[mf] = *(const short8 *)(Al + off);
    }
#pragma unroll
    for (int nf = 0; nf < 4; ++nf) {
      const size_t off = (size_t)(bn + nf * 16 + lr) * DMODEL + k0 + lq * 8;
      bh[nf] = *(const short8 *)(Bh + off);
      bl[nf] = *(const short8 *)(Bl + off);
    }
#pragma unroll
    for (int mf = 0; mf < 2; ++mf)
#pragma unroll
      for (int nf = 0; nf < 4; ++nf) {
        acc[mf][nf] = __builtin_amdgcn_mfma_f32_16x16x32_bf16(
            ah[mf], bh[nf], acc[mf][nf], 0, 0, 0);
        acc[mf][nf] = __builtin_amdgcn_mfma_f32_16x16x32_bf16(
            ah[mf], bl[nf], acc[mf][nf], 0, 0, 0);
        acc[mf][nf] = __builtin_amdgcn_mfma_f32_16x16x32_bf16(
            al[mf], bh[nf], acc[mf][nf], 0, 0, 0);
      }
  }

#pragma unroll
  for (int mf = 0; mf < 2; ++mf)
#pragma unroll
    for (int nf = 0; nf < 4; ++nf) {
      const int gn2 = am + mf * 16 + lq * 4;
#pragma unroll
      for (int r = 0; r < 4; ++r) {
        const int featl = (w * 32 + mf * 16 + lq * 4 + r);
        Tt[featl * 72 + nf * 16 + lr] =
            f2bf_rne(acc[mf][nf][r] + bias[gn2 + r]);
      }
    }
  __syncthreads();
  const int feat = tid >> 1, half = tid & 1;
  const int gfeat = blockIdx.y * 128 + feat;
  const int bcol = bn >> 11, scol = (bn & 2047) + half * 32;
  ushort *dst = Y + ((size_t)(bcol * DMODEL + gfeat)) * SQ + scol;
  const ushort *srcp = &Tt[feat * 72 + half * 32];
#pragma unroll
  for (int j = 0; j < 4; ++j)
    *(uint4 *)(dst + j * 8) = *(const uint4 *)(srcp + j * 8);
}

// ---------------- MFMA attention, fused masks, double-buffered staging ------
__global__ __launch_bounds__(256, 2) void attn_mfma(
    const ushort *__restrict__ qp, const ushort *__restrict__ kp,
    const ushort *__restrict__ vpt, ushort *__restrict__ xah,
    ushort *__restrict__ xal, TfArgs ta) {
  __shared__ __align__(16) uint8_t lds[40960];
  const int b = blockIdx.z, h = blockIdx.y;
  const int qb = blockIdx.x * 64;
  const int tid = threadIdx.x;
  const int w = tid >> 6, l = tid & 63;
  const int lr = l & 15, lq = l >> 4;
  uint8_t *Ps = lds + 32768 + w * 2048;
  const int bh = b * NH + h;

  short8 qf[2];
  {
    const int qrow = qb + w * 16 + lr;
    const ushort *qrowp = qp + ((size_t)(b * SQ + qrow)) * DMODEL + h * DK;
    qf[0] = *(const short8 *)(qrowp + lq * 8);
    qf[1] = *(const short8 *)(qrowp + 32 + lq * 8);
  }
  f32x4 o[4];
  f32x4 lacc;
#pragma unroll
  for (int nd = 0; nd < 4; ++nd) o[nd] = (f32x4){0.f, 0.f, 0.f, 0.f};
  lacc = (f32x4){0.f, 0.f, 0.f, 0.f};

  uint32_t rowflat[4];
#pragma unroll
  for (int r = 0; r < 4; ++r)
    rowflat[r] = ((uint32_t)(bh * SQ + qb + w * 16 + lq * 4 + r)) << 11;

  const int srow = tid >> 2;
  const int sc0 = (tid & 3) * 2;
  const int ssw = (srow & 7) << 4;
  const ushort *kbase =
      kp + ((size_t)(b * SQ) + srow) * DMODEL + h * DK + sc0 * 8;
  const ushort *vbase = vpt + ((size_t)(bh * DK + srow)) * SQ + sc0 * 8;
  const int la0 = (srow * 128 + sc0 * 16) ^ ssw;
  const int la1 = (srow * 128 + (sc0 + 1) * 16) ^ ssw;

  uint4 kr0, kr1, vr0, vr1;
#define ISSUE(kv_)                                            \
  {                                                           \
    const ushort *ks_ = kbase + (size_t)(kv_)*DMODEL;         \
    kr0 = *(const uint4 *)ks_;                                \
    kr1 = *(const uint4 *)(ks_ + 8);                          \
    const ushort *vs_ = vbase + (kv_);                        \
    vr0 = *(const uint4 *)vs_;                                \
    vr1 = *(const uint4 *)(vs_ + 8);                          \
  }
#define STORE(buf_)                                           \
  {                                                           \
    uint8_t *Kb_ = lds + (buf_)*8192;                         \
    uint8_t *Vb_ = lds + 16384 + (buf_)*8192;                 \
    *(uint4 *)(Kb_ + la0) = kr0;                              \
    *(uint4 *)(Kb_ + la1) = kr1;                              \
    *(uint4 *)(Vb_ + la0) = vr0;                              \
    *(uint4 *)(Vb_ + la1) = vr1;                              \
  }

  ISSUE(0)
  STORE(0)
  __syncthreads();

  for (int kv = 0; kv < SQ; kv += 64) {
    const int cur = (kv >> 6) & 1;
    uint8_t *Ks = lds + cur * 8192;
    uint8_t *Vt = lds + 16384 + cur * 8192;
    const bool more = (kv + 64) < SQ;
    if (more) ISSUE(kv + 64)

    f32x4 s[4];
#pragma unroll
    for (int ni = 0; ni < 4; ++ni) s[ni] = (f32x4){0.f, 0.f, 0.f, 0.f};
#pragma unroll
    for (int ni = 0; ni < 4; ++ni) {
      const int krow = ni * 16 + lr;
      const int sw = (krow & 7) << 4;
#pragma unroll
      for (int kf = 0; kf < 2; ++kf) {
        short8 kb =
            *(const short8 *)(Ks + ((krow * 128 + kf * 64 + lq * 16) ^ sw));
        s[ni] =
            __builtin_amdgcn_mfma_f32_16x16x32_bf16(qf[kf], kb, s[ni], 0, 0, 0);
      }
    }

    const uint32_t colbase = (uint32_t)(kv + lr);
#pragma unroll
    for (int ni = 0; ni < 4; ++ni) {
#pragma unroll
      for (int r = 0; r < 4; ++r) {
        const uint32_t ctr = rowflat[r] + colbase + (uint32_t)(ni * 16);
        const bool keep_s = tf_rt(ta.sp, ctr) >= ta.sp_thr;
        const bool keep_d = tf_rt(ta.dp, ctr) >= ta.dp_thr;
        float e = exp_scaled(s[ni][r]);
        float p = keep_s ? e : 0.0f;
        lacc[r] += p;
        float pd = keep_d ? p * (1.0f / 0.9f) : 0.0f;
        const int prow = lq * 4 + r;
        *(ushort *)(Ps +
                    ((prow * 128 + (ni * 16 + lr) * 2) ^ ((prow & 7) << 4))) =
            f2bf_rne(pd);
      }
    }

#pragma unroll
    for (int kf = 0; kf < 2; ++kf) {
      short8 pa = *(const short8 *)(Ps + ((lr * 128 + kf * 64 + lq * 16) ^
                                          ((lr & 7) << 4)));
#pragma unroll
      for (int nd = 0; nd < 4; ++nd) {
        const int vrow = nd * 16 + lr;
        short8 vb = *(const short8 *)(Vt + ((vrow * 128 + kf * 64 + lq * 16) ^
                                            ((vrow & 7) << 4)));
        o[nd] = __builtin_amdgcn_mfma_f32_16x16x32_bf16(pa, vb, o[nd], 0, 0, 0);
      }
    }

    if (more) STORE(cur ^ 1)
    __syncthreads();
  }
#undef ISSUE
#undef STORE

  float inv[4];
#pragma unroll
  for (int r = 0; r < 4; ++r) {
    float t = lacc[r];
    t += __shfl_xor(t, 1);
    t += __shfl_xor(t, 2);
    t += __shfl_xor(t, 4);
    t += __shfl_xor(t, 8);
    inv[r] = 1.0f / t;
  }
#pragma unroll
  for (int nd = 0; nd < 4; ++nd)
#pragma unroll
    for (int r = 0; r < 4; ++r) {
      const int qrow = qb + w * 16 + lq * 4 + r;
      const size_t idx =
          ((size_t)(b * SQ + qrow)) * DMODEL + h * DK + nd * 16 + lr;
      const float val = o[nd][r] * inv[r];
      const ushort hh = f2bf_rne(val);
      xah[idx] = hh;
      xal[idx] = f2bf_rne(val - bf2f(hh));
    }
}

// ---------------------------------------------------------------------------
extern "C" void kernel_launch(void *const *d_in, const int *in_sizes, int n_in,
                              void *d_out, int out_size, void *d_ws,
                              size_t ws_size, hipStream_t stream) {
  (void)in_sizes; (void)n_in; (void)out_size;
  const float *query = (const float *)d_in[0];
  const float *key_  = (const float *)d_in[1];
  const float *value = (const float *)d_in[2];
  const float *Wq = (const float *)d_in[3];
  const float *bq = (const float *)d_in[4];
  const float *Wk = (const float *)d_in[5];
  const float *bk = (const float *)d_in[6];
  const float *Wv = (const float *)d_in[7];
  const float *bv = (const float *)d_in[8];
  const float *Wo = (const float *)d_in[9];
  const float *bo = (const float *)d_in[10];
  float *out = (float *)d_out;

  const size_t MB = (size_t)1 << 20;
  if (ws_size < 60 * MB) return;

  char *ws = (char *)d_ws;
  ushort *vih = (ushort *)(ws);                          // 8 MB
  ushort *vil = (ushort *)(ws + 8 * MB);                 // 8 MB
  ushort *Wqh = (ushort *)(ws + 16 * MB);
  ushort *Wql = (ushort *)(ws + 16 * MB + 512 * 1024);
  ushort *Wkh = (ushort *)(ws + 17 * MB);
  ushort *Wkl = (ushort *)(ws + 17 * MB + 512 * 1024);
  ushort *Wvh = (ushort *)(ws + 18 * MB);
  ushort *Wvl = (ushort *)(ws + 18 * MB + 512 * 1024);
  ushort *Woh = (ushort *)(ws + 19 * MB);
  ushort *Wol = (ushort *)(ws + 19 * MB + 512 * 1024);
  ushort *qp  = (ushort *)(ws + 20 * MB);                // 8 MB
  ushort *kp  = (ushort *)(ws + 28 * MB);                // 8 MB
  ushort *vpt = (ushort *)(ws + 36 * MB);                // 8 MB
  ushort *xah = (ushort *)(ws + 44 * MB);                // 8 MB
  ushort *xal = (ushort *)(ws + 52 * MB);                // 8 MB

  constexpr uint32_t KS2s = SPK.a ^ SPK.b ^ 0x1BD11BDAu;
  constexpr uint32_t KS2d = DPK.a ^ DPK.b ^ 0x1BD11BDAu;
  TfArgs ta = {
      {SPK.a, SPK.b, KS2s + 1u, SPK.a + 2u, SPK.b + 3u, KS2s + 4u, SPK.a + 5u,
       KS2s},
      {DPK.a, DPK.b, KS2d + 1u, DPK.a + 2u, DPK.b + 3u, KS2d + 4u, DPK.a + 5u,
       KS2d},
      SP_THR, DP_THR};

  // value + all 4 weights split in one launch (4096 + 4*256 blocks)
  split_all<<<5120, 256, 0, stream>>>(value, Wq, Wk, Wv, Wo, vih, vil, Wqh,
                                      Wql, Wkh, Wkl, Wvh, Wvl, Woh, Wol);

  // Q and K projections fused (A read fp32, split in-register)
  proj_qk<<<dim3(2, 128, 2), 256, 0, stream>>>(query, key_, Wqh, Wql, Wkh, Wkl,
                                               bq, bk, qp, kp);

  // V projection -> per-head V^T
  proj_vt<<<dim3(128, 4), 256, 0, stream>>>(Wvh, Wvl, vih, vil, bv, vpt);

  attn_mfma<<<dim3(SQ / 64, NH, BATCH), 256, 0, stream>>>(qp, kp, vpt, xah,
                                                          xal, ta);

  proj_out<<<dim3(4, 128), 256, 0, stream>>>(xah, xal, Woh, Wol, bo, out);
}

// Round 8
// 705.967 us; speedup vs baseline: 1.1112x; 1.0737x over previous
//
#include <hip/hip_runtime.h>
#include <stdint.h>

#define BATCH  4
#define SQ     2048
#define DMODEL 512
#define NH     8
#define DK     64

typedef __attribute__((ext_vector_type(8))) short short8;
typedef __attribute__((ext_vector_type(4))) float f32x4;

// ---------------- threefry2x32 (JAX-compatible, 20 rounds) ----------------
struct TFK { uint32_t a, b; };
constexpr uint32_t rotl_ce(uint32_t x, int d) {
  return (x << d) | (x >> (32 - d));
}
constexpr TFK tf_ce(uint32_t k0, uint32_t k1, uint32_t x0, uint32_t x1) {
  const uint32_t ks[3] = {k0, k1, k0 ^ k1 ^ 0x1BD11BDAu};
  const int rot[2][4] = {{13, 15, 26, 6}, {17, 29, 16, 24}};
  x0 += k0; x1 += k1;
  for (int c = 0; c < 5; ++c) {
    for (int j = 0; j < 4; ++j) {
      x0 += x1; x1 = rotl_ce(x1, rot[c & 1][j]); x1 ^= x0;
    }
    x0 += ks[(c + 1) % 3];
    x1 += ks[(c + 2) % 3] + (uint32_t)(c + 1);
  }
  return TFK{x0, x1};
}
constexpr TFK SPK = tf_ce(0u, 42u, 0u, 1u);  // fold_in(key(42), 1)
constexpr TFK DPK = tf_ce(0u, 42u, 0u, 2u);  // fold_in(key(42), 2)

#define SP_THR 0x80000200u
#define DP_THR 0x1999A200u

// Key-schedule constants as kernel args (SGPR-resident).
struct TfArgs {
  uint32_t sp[8];
  uint32_t dp[8];
  uint32_t sp_thr, dp_thr;
};

__device__ __forceinline__ void tf_round(uint32_t &x0, uint32_t &x1, int d) {
  x0 += x1;
  x1 = __builtin_amdgcn_alignbit(x1, x1, 32 - d);
  x1 ^= x0;
}
__device__ __forceinline__ void tf_grp(uint32_t &x0, uint32_t &x1,
                                       uint32_t injx1, uint32_t injx0, int d0,
                                       int d1, int d2, int d3) {
  x1 += injx1;
  x0 = x0 + injx0 + x1;
  x1 = __builtin_amdgcn_alignbit(x1, x1, 32 - d0);
  x1 ^= x0;
  tf_round(x0, x1, d1);
  tf_round(x0, x1, d2);
  tf_round(x0, x1, d3);
}
__device__ __forceinline__ uint32_t tf_rt(const uint32_t *__restrict__ c,
                                          uint32_t ctr) {
  uint32_t x1 = c[1] + ctr;
  uint32_t x0 = c[0] + x1;
  x1 = __builtin_amdgcn_alignbit(x1, x1, 19);
  x1 ^= x0;
  tf_round(x0, x1, 15);
  tf_round(x0, x1, 26);
  tf_round(x0, x1, 6);
  tf_grp(x0, x1, c[2], c[1], 17, 29, 16, 24);
  tf_grp(x0, x1, c[3], c[7], 13, 15, 26, 6);
  tf_grp(x0, x1, c[4], c[0], 17, 29, 16, 24);
  tf_grp(x0, x1, c[5], c[1], 13, 15, 26, 6);
  return (x0 + c[7]) ^ (x1 + c[6]);
}

__device__ __forceinline__ ushort f2bf_rne(float f) {
  uint32_t u = __float_as_uint(f);
  return (ushort)((u + 0x7fffu + ((u >> 16) & 1u)) >> 16);
}
__device__ __forceinline__ float bf2f(ushort h) {
  return __uint_as_float((uint32_t)h << 16);
}
__device__ __forceinline__ float exp_scaled(float s) {  // exp(s/8)
#if __has_builtin(__builtin_amdgcn_exp2f)
  return __builtin_amdgcn_exp2f(s * 0.18033688011112042f);
#else
  return __expf(s * 0.125f);
#endif
}

// ---------------- hi/lo split: q,k,v + 4 weights in ONE kernel --------------
__device__ __forceinline__ void split4(const float *__restrict__ src,
                                       ushort *__restrict__ dh,
                                       ushort *__restrict__ dl, size_t base) {
  float4 x = *(const float4 *)(src + base);
  uint32_t h[4], lo[4];
#pragma unroll
  for (int i = 0; i < 4; ++i) {
    float xi = ((const float *)&x)[i];
    ushort hh = f2bf_rne(xi);
    h[i] = hh;
    lo[i] = f2bf_rne(xi - bf2f(hh));
  }
  uint2 ph, pl;
  ph.x = h[0] | (h[1] << 16);  ph.y = h[2] | (h[3] << 16);
  pl.x = lo[0] | (lo[1] << 16); pl.y = lo[2] | (lo[3] << 16);
  *(uint2 *)(dh + base) = ph;
  *(uint2 *)(dl + base) = pl;
}

__global__ __launch_bounds__(256) void split_all(
    const float *__restrict__ q, const float *__restrict__ k,
    const float *__restrict__ v, const float *__restrict__ Wq,
    const float *__restrict__ Wk, const float *__restrict__ Wv,
    const float *__restrict__ Wo, ushort *__restrict__ qh,
    ushort *__restrict__ ql, ushort *__restrict__ kh, ushort *__restrict__ kl,
    ushort *__restrict__ vh, ushort *__restrict__ vl, ushort *__restrict__ Wqh,
    ushort *__restrict__ Wql, ushort *__restrict__ Wkh,
    ushort *__restrict__ Wkl, ushort *__restrict__ Wvh,
    ushort *__restrict__ Wvl, ushort *__restrict__ Woh,
    ushort *__restrict__ Wol) {
  const int bid = blockIdx.x;
  const float *src;
  ushort *dh, *dl;
  uint32_t lb;
  if (bid < 12288) {  // q,k,v: 4096 blocks each
    const int which = bid >> 12;
    lb = bid & 4095;
    src = which == 0 ? q : (which == 1 ? k : v);
    dh = which == 0 ? qh : (which == 1 ? kh : vh);
    dl = which == 0 ? ql : (which == 1 ? kl : vl);
  } else {  // weights: 256 blocks each
    const int t = bid - 12288;
    const int wsel = t >> 8;
    lb = t & 255;
    src = wsel == 0 ? Wq : (wsel == 1 ? Wk : (wsel == 2 ? Wv : Wo));
    dh = wsel == 0 ? Wqh : (wsel == 1 ? Wkh : (wsel == 2 ? Wvh : Woh));
    dl = wsel == 0 ? Wql : (wsel == 1 ? Wkl : (wsel == 2 ? Wvl : Wol));
  }
  const size_t base = ((size_t)lb * 256 + threadIdx.x) * 4;
  split4(src, dh, dl, base);
}

// ---------------- hi/lo bf16 MFMA GEMM core (R5-proven geometry) ------------
// D = A @ B^T (+bias); A [M][512], B [N][512], hi/lo bf16.
// Block: 128 A-rows x 64 B-rows; 4 waves of 32x64 (2x4 16x16 frags).
// MODE 0: fp32 out, bias[col].  MODE 1: bf16 out, bias[col].
// MODE 2: bf16 transposed per-head vpt out, bias[row], via LDS transpose.
template <int MODE>
__device__ __forceinline__ void proj_core(const ushort *__restrict__ Ah,
                                          const ushort *__restrict__ Al,
                                          const ushort *__restrict__ Bh,
                                          const ushort *__restrict__ Bl,
                                          const float *__restrict__ bias,
                                          void *__restrict__ Yv) {
  __shared__ ushort Tt[MODE == 2 ? 128 * 72 : 1];
  const int tid = threadIdx.x;
  const int w = tid >> 6, l = tid & 63;
  const int lr = l & 15, lq = l >> 4;
  const int am = blockIdx.y * 128 + w * 32;
  const int bn = blockIdx.x * 64;
  f32x4 acc[2][4];
#pragma unroll
  for (int i = 0; i < 2; ++i)
#pragma unroll
    for (int j = 0; j < 4; ++j) acc[i][j] = (f32x4){0.f, 0.f, 0.f, 0.f};

#pragma unroll 2
  for (int k0 = 0; k0 < DMODEL; k0 += 32) {
    short8 ah[2], al[2], bh[4], bl[4];
#pragma unroll
    for (int mf = 0; mf < 2; ++mf) {
      const size_t off = (size_t)(am + mf * 16 + lr) * DMODEL + k0 + lq * 8;
      ah[mf] = *(const short8 *)(Ah + off);
      al[mf] = *(const short8 *)(Al + off);
    }
#pragma unroll
    for (int nf = 0; nf < 4; ++nf) {
      const size_t off = (size_t)(bn + nf * 16 + lr) * DMODEL + k0 + lq * 8;
      bh[nf] = *(const short8 *)(Bh + off);
      bl[nf] = *(const short8 *)(Bl + off);
    }
#pragma unroll
    for (int mf = 0; mf < 2; ++mf)
#pragma unroll
      for (int nf = 0; nf < 4; ++nf) {
        acc[mf][nf] = __builtin_amdgcn_mfma_f32_16x16x32_bf16(
            ah[mf], bh[nf], acc[mf][nf], 0, 0, 0);
        acc[mf][nf] = __builtin_amdgcn_mfma_f32_16x16x32_bf16(
            ah[mf], bl[nf], acc[mf][nf], 0, 0, 0);
        acc[mf][nf] = __builtin_amdgcn_mfma_f32_16x16x32_bf16(
            al[mf], bh[nf], acc[mf][nf], 0, 0, 0);
      }
  }

  if (MODE == 2) {
#pragma unroll
    for (int mf = 0; mf < 2; ++mf)
#pragma unroll
      for (int nf = 0; nf < 4; ++nf) {
        const int gn2 = am + mf * 16 + lq * 4;
#pragma unroll
        for (int r = 0; r < 4; ++r) {
          const int featl = (w * 32 + mf * 16 + lq * 4 + r);
          Tt[featl * 72 + nf * 16 + lr] =
              f2bf_rne(acc[mf][nf][r] + bias[gn2 + r]);
        }
      }
    __syncthreads();
    ushort *Y = (ushort *)Yv;
    const int feat = tid >> 1, half = tid & 1;
    const int gfeat = blockIdx.y * 128 + feat;
    const int bcol = bn >> 11, scol = (bn & 2047) + half * 32;
    ushort *dst = Y + ((size_t)(bcol * DMODEL + gfeat)) * SQ + scol;
    const ushort *srcp = &Tt[feat * 72 + half * 32];
#pragma unroll
    for (int j = 0; j < 4; ++j)
      *(uint4 *)(dst + j * 8) = *(const uint4 *)(srcp + j * 8);
  } else {
#pragma unroll
    for (int mf = 0; mf < 2; ++mf)
#pragma unroll
      for (int nf = 0; nf < 4; ++nf) {
        const int gn = bn + nf * 16 + lr;
        const float bb = bias[gn];
        if (MODE == 0) {
          float *Y = (float *)Yv;
#pragma unroll
          for (int r = 0; r < 4; ++r) {
            const int gm = am + mf * 16 + lq * 4 + r;
            Y[(size_t)gm * DMODEL + gn] = acc[mf][nf][r] + bb;
          }
        } else {
          ushort *Y = (ushort *)Yv;
#pragma unroll
          for (int r = 0; r < 4; ++r) {
            const int gm = am + mf * 16 + lq * 4 + r;
            Y[(size_t)gm * DMODEL + gn] = f2bf_rne(acc[mf][nf][r] + bb);
          }
        }
      }
  }
}

// Q and K projections fused via blockIdx.z.
__global__ __launch_bounds__(256) void proj_qk(
    const ushort *__restrict__ qih, const ushort *__restrict__ qil,
    const ushort *__restrict__ kih, const ushort *__restrict__ kil,
    const ushort *__restrict__ Wqh, const ushort *__restrict__ Wql,
    const ushort *__restrict__ Wkh, const ushort *__restrict__ Wkl,
    const float *__restrict__ bq, const float *__restrict__ bk,
    ushort *__restrict__ qp, ushort *__restrict__ kp) {
  if (blockIdx.z == 0)
    proj_core<1>(qih, qil, Wqh, Wql, bq, qp);
  else
    proj_core<1>(kih, kil, Wkh, Wkl, bk, kp);
}

// V projection -> per-head V^T (A = Wv feats, B = value rows).
__global__ __launch_bounds__(256) void proj_v(
    const ushort *__restrict__ Wvh, const ushort *__restrict__ Wvl,
    const ushort *__restrict__ vih, const ushort *__restrict__ vil,
    const float *__restrict__ bv, ushort *__restrict__ vpt) {
  proj_core<2>(Wvh, Wvl, vih, vil, bv, vpt);
}

// Output projection (fp32 out).
__global__ __launch_bounds__(256) void proj_o(
    const ushort *__restrict__ xah, const ushort *__restrict__ xal,
    const ushort *__restrict__ Woh, const ushort *__restrict__ Wol,
    const float *__restrict__ bo, float *__restrict__ out) {
  proj_core<0>(xah, xal, Woh, Wol, bo, out);
}

// ---------------- MFMA attention, fused masks, double-buffered staging ------
__global__ __launch_bounds__(256, 4) void attn_mfma(
    const ushort *__restrict__ qp, const ushort *__restrict__ kp,
    const ushort *__restrict__ vpt, ushort *__restrict__ xah,
    ushort *__restrict__ xal, TfArgs ta) {
  __shared__ __align__(16) uint8_t lds[40960];
  const int b = blockIdx.z, h = blockIdx.y;
  const int qb = blockIdx.x * 64;
  const int tid = threadIdx.x;
  const int w = tid >> 6, l = tid & 63;
  const int lr = l & 15, lq = l >> 4;
  uint8_t *Ps = lds + 32768 + w * 2048;
  const int bh = b * NH + h;

  short8 qf[2];
  {
    const int qrow = qb + w * 16 + lr;
    const ushort *qrowp = qp + ((size_t)(b * SQ + qrow)) * DMODEL + h * DK;
    qf[0] = *(const short8 *)(qrowp + lq * 8);
    qf[1] = *(const short8 *)(qrowp + 32 + lq * 8);
  }
  f32x4 o[4];
  f32x4 lacc;
#pragma unroll
  for (int nd = 0; nd < 4; ++nd) o[nd] = (f32x4){0.f, 0.f, 0.f, 0.f};
  lacc = (f32x4){0.f, 0.f, 0.f, 0.f};

  uint32_t rowflat[4];
#pragma unroll
  for (int r = 0; r < 4; ++r)
    rowflat[r] = ((uint32_t)(bh * SQ + qb + w * 16 + lq * 4 + r)) << 11;

  const int srow = tid >> 2;
  const int sc0 = (tid & 3) * 2;
  const int ssw = (srow & 7) << 4;
  const ushort *kbase =
      kp + ((size_t)(b * SQ) + srow) * DMODEL + h * DK + sc0 * 8;
  const ushort *vbase = vpt + ((size_t)(bh * DK + srow)) * SQ + sc0 * 8;
  const int la0 = (srow * 128 + sc0 * 16) ^ ssw;
  const int la1 = (srow * 128 + (sc0 + 1) * 16) ^ ssw;

  uint4 kr0, kr1, vr0, vr1;
#define ISSUE(kv_)                                            \
  {                                                           \
    const ushort *ks_ = kbase + (size_t)(kv_)*DMODEL;         \
    kr0 = *(const uint4 *)ks_;                                \
    kr1 = *(const uint4 *)(ks_ + 8);                          \
    const ushort *vs_ = vbase + (kv_);                        \
    vr0 = *(const uint4 *)vs_;                                \
    vr1 = *(const uint4 *)(vs_ + 8);                          \
  }
#define STORE(buf_)                                           \
  {                                                           \
    uint8_t *Kb_ = lds + (buf_)*8192;                         \
    uint8_t *Vb_ = lds + 16384 + (buf_)*8192;                 \
    *(uint4 *)(Kb_ + la0) = kr0;                              \
    *(uint4 *)(Kb_ + la1) = kr1;                              \
    *(uint4 *)(Vb_ + la0) = vr0;                              \
    *(uint4 *)(Vb_ + la1) = vr1;                              \
  }

  ISSUE(0)
  STORE(0)
  __syncthreads();

  for (int kv = 0; kv < SQ; kv += 64) {
    const int cur = (kv >> 6) & 1;
    uint8_t *Ks = lds + cur * 8192;
    uint8_t *Vt = lds + 16384 + cur * 8192;
    const bool more = (kv + 64) < SQ;
    if (more) ISSUE(kv + 64)

    f32x4 s[4];
#pragma unroll
    for (int ni = 0; ni < 4; ++ni) s[ni] = (f32x4){0.f, 0.f, 0.f, 0.f};
#pragma unroll
    for (int ni = 0; ni < 4; ++ni) {
      const int krow = ni * 16 + lr;
      const int sw = (krow & 7) << 4;
#pragma unroll
      for (int kf = 0; kf < 2; ++kf) {
        short8 kb =
            *(const short8 *)(Ks + ((krow * 128 + kf * 64 + lq * 16) ^ sw));
        s[ni] =
            __builtin_amdgcn_mfma_f32_16x16x32_bf16(qf[kf], kb, s[ni], 0, 0, 0);
      }
    }

    const uint32_t colbase = (uint32_t)(kv + lr);
#pragma unroll
    for (int ni = 0; ni < 4; ++ni) {
#pragma unroll
      for (int r = 0; r < 4; ++r) {
        const uint32_t ctr = rowflat[r] + colbase + (uint32_t)(ni * 16);
        const bool keep_s = tf_rt(ta.sp, ctr) >= ta.sp_thr;
        const bool keep_d = tf_rt(ta.dp, ctr) >= ta.dp_thr;
        float e = exp_scaled(s[ni][r]);
        float p = keep_s ? e : 0.0f;
        lacc[r] += p;
        float pd = keep_d ? p * (1.0f / 0.9f) : 0.0f;
        const int prow = lq * 4 + r;
        *(ushort *)(Ps +
                    ((prow * 128 + (ni * 16 + lr) * 2) ^ ((prow & 7) << 4))) =
            f2bf_rne(pd);
      }
    }

#pragma unroll
    for (int kf = 0; kf < 2; ++kf) {
      short8 pa = *(const short8 *)(Ps + ((lr * 128 + kf * 64 + lq * 16) ^
                                          ((lr & 7) << 4)));
#pragma unroll
      for (int nd = 0; nd < 4; ++nd) {
        const int vrow = nd * 16 + lr;
        short8 vb = *(const short8 *)(Vt + ((vrow * 128 + kf * 64 + lq * 16) ^
                                            ((vrow & 7) << 4)));
        o[nd] = __builtin_amdgcn_mfma_f32_16x16x32_bf16(pa, vb, o[nd], 0, 0, 0);
      }
    }

    if (more) STORE(cur ^ 1)
    __syncthreads();
  }
#undef ISSUE
#undef STORE

  float inv[4];
#pragma unroll
  for (int r = 0; r < 4; ++r) {
    float t = lacc[r];
    t += __shfl_xor(t, 1);
    t += __shfl_xor(t, 2);
    t += __shfl_xor(t, 4);
    t += __shfl_xor(t, 8);
    inv[r] = 1.0f / t;
  }
#pragma unroll
  for (int nd = 0; nd < 4; ++nd)
#pragma unroll
    for (int r = 0; r < 4; ++r) {
      const int qrow = qb + w * 16 + lq * 4 + r;
      const size_t idx =
          ((size_t)(b * SQ + qrow)) * DMODEL + h * DK + nd * 16 + lr;
      const float val = o[nd][r] * inv[r];
      const ushort hh = f2bf_rne(val);
      xah[idx] = hh;
      xal[idx] = f2bf_rne(val - bf2f(hh));
    }
}

// ---------------------------------------------------------------------------
extern "C" void kernel_launch(void *const *d_in, const int *in_sizes, int n_in,
                              void *d_out, int out_size, void *d_ws,
                              size_t ws_size, hipStream_t stream) {
  (void)in_sizes; (void)n_in; (void)out_size;
  const float *query = (const float *)d_in[0];
  const float *key_  = (const float *)d_in[1];
  const float *value = (const float *)d_in[2];
  const float *Wq = (const float *)d_in[3];
  const float *bq = (const float *)d_in[4];
  const float *Wk = (const float *)d_in[5];
  const float *bk = (const float *)d_in[6];
  const float *Wv = (const float *)d_in[7];
  const float *bv = (const float *)d_in[8];
  const float *Wo = (const float *)d_in[9];
  const float *bo = (const float *)d_in[10];
  float *out = (float *)d_out;

  const size_t MB = (size_t)1 << 20;
  if (ws_size < 92 * MB) return;

  char *ws = (char *)d_ws;
  ushort *qih = (ushort *)(ws);
  ushort *qil = (ushort *)(ws + 8 * MB);
  ushort *kih = (ushort *)(ws + 16 * MB);
  ushort *kil = (ushort *)(ws + 24 * MB);
  ushort *vih = (ushort *)(ws + 32 * MB);
  ushort *vil = (ushort *)(ws + 40 * MB);
  ushort *Wqh = (ushort *)(ws + 48 * MB);
  ushort *Wql = (ushort *)(ws + 48 * MB + 512 * 1024);
  ushort *Wkh = (ushort *)(ws + 49 * MB);
  ushort *Wkl = (ushort *)(ws + 49 * MB + 512 * 1024);
  ushort *Wvh = (ushort *)(ws + 50 * MB);
  ushort *Wvl = (ushort *)(ws + 50 * MB + 512 * 1024);
  ushort *Woh = (ushort *)(ws + 51 * MB);
  ushort *Wol = (ushort *)(ws + 51 * MB + 512 * 1024);
  ushort *qp  = (ushort *)(ws + 52 * MB);
  ushort *kp  = (ushort *)(ws + 60 * MB);
  ushort *vpt = (ushort *)(ws + 68 * MB);
  ushort *xah = (ushort *)(ws + 76 * MB);
  ushort *xal = (ushort *)(ws + 84 * MB);

  constexpr uint32_t KS2s = SPK.a ^ SPK.b ^ 0x1BD11BDAu;
  constexpr uint32_t KS2d = DPK.a ^ DPK.b ^ 0x1BD11BDAu;
  TfArgs ta = {
      {SPK.a, SPK.b, KS2s + 1u, SPK.a + 2u, SPK.b + 3u, KS2s + 4u, SPK.a + 5u,
       KS2s},
      {DPK.a, DPK.b, KS2d + 1u, DPK.a + 2u, DPK.b + 3u, KS2d + 4u, DPK.a + 5u,
       KS2d},
      SP_THR, DP_THR};

  // q,k,v + all 4 weights split in one launch
  split_all<<<13312, 256, 0, stream>>>(query, key_, value, Wq, Wk, Wv, Wo, qih,
                                       qil, kih, kil, vih, vil, Wqh, Wql, Wkh,
                                       Wkl, Wvh, Wvl, Woh, Wol);

  // Q and K projections fused (R5-proven geometry)
  proj_qk<<<dim3(8, 64, 2), 256, 0, stream>>>(qih, qil, kih, kil, Wqh, Wql,
                                              Wkh, Wkl, bq, bk, qp, kp);

  // V projection -> per-head V^T
  proj_v<<<dim3(128, 4), 256, 0, stream>>>(Wvh, Wvl, vih, vil, bv, vpt);

  attn_mfma<<<dim3(SQ / 64, NH, BATCH), 256, 0, stream>>>(qp, kp, vpt, xah,
                                                          xal, ta);

  proj_o<<<dim3(8, 64), 256, 0, stream>>>(xah, xal, Woh, Wol, bo, out);
}